// Round 4
// baseline (797.763 us; speedup 1.0000x reference)
//
#include <hip/hip_runtime.h>
#include <stdint.h>

#define NT 8192      // tokens
#define DM 1024      // d_model
#define DF 2048      // d_ff
#define RT_BLOCKS 256

typedef __attribute__((ext_vector_type(8))) short short8;
typedef __attribute__((ext_vector_type(4))) float f32x4;

__device__ __forceinline__ unsigned short f2bf(float f) {
  uint32_t x = __float_as_uint(f);
  return (unsigned short)((x + 0x7fffu + ((x >> 16) & 1u)) >> 16);
}

__device__ __forceinline__ void gload16(const void* g, void* l) {
  __builtin_amdgcn_global_load_lds(
      (const __attribute__((address_space(1))) uint32_t*)g,
      (__attribute__((address_space(3))) uint32_t*)l, 16, 0, 0);
}

// ---------------- fp32 -> bf16 for the 3 weight tensors (one launch) ----------------
__global__ void k_cvt3(const float4* __restrict__ s0, const float4* __restrict__ s1,
                       const float4* __restrict__ s2,
                       ushort4* __restrict__ d0, ushort4* __restrict__ d1,
                       ushort4* __restrict__ d2, int n4) {
  int w = blockIdx.y;
  const float4* src = (w == 0) ? s0 : (w == 1) ? s1 : s2;
  ushort4* dst = (w == 0) ? d0 : (w == 1) ? d1 : d2;
  int i = blockIdx.x * blockDim.x + threadIdx.x;
  int st = gridDim.x * blockDim.x;
  for (; i < n4; i += st) {
    float4 v = src[i];
    ushort4 o;
    o.x = f2bf(v.x); o.y = f2bf(v.y); o.z = f2bf(v.z); o.w = f2bf(v.w);
    dst[i] = o;
  }
}

// ---------------- router: logits, softmax, top2, losses; also emits x in bf16 ----------------
__global__ void k_router(const float* __restrict__ x, const float* __restrict__ wr,
                         int* cntb, int* cnt1, float* imp, float* z2,
                         int* epack, float2* gts, unsigned short* __restrict__ xbf) {
  int lane = threadIdx.x & 63;
  int wid = threadIdx.x >> 6;
  const float4* w4 = (const float4*)wr;

  float imp_acc[8] = {0.f, 0.f, 0.f, 0.f, 0.f, 0.f, 0.f, 0.f};
  float z2_acc = 0.f;
  int cb_acc[8] = {0, 0, 0, 0, 0, 0, 0, 0};
  int c1_acc[8] = {0, 0, 0, 0, 0, 0, 0, 0};

  for (int t = blockIdx.x * 4 + wid; t < NT; t += RT_BLOCKS * 4) {
    const float4* x4 = (const float4*)(x + (size_t)t * DM);
    ushort4* xb4 = (ushort4*)(xbf + (size_t)t * DM);
    float4 xv[4];
    #pragma unroll
    for (int j = 0; j < 4; ++j) {
      xv[j] = x4[lane + 64 * j];
      ushort4 o;
      o.x = f2bf(xv[j].x); o.y = f2bf(xv[j].y); o.z = f2bf(xv[j].z); o.w = f2bf(xv[j].w);
      xb4[lane + 64 * j] = o;
    }
    float p[8];
    #pragma unroll
    for (int e = 0; e < 8; ++e) p[e] = 0.f;
    #pragma unroll
    for (int j = 0; j < 4; ++j) {
      #pragma unroll
      for (int e = 0; e < 8; ++e) {
        float4 wv = w4[e * 256 + lane + 64 * j];
        p[e] += xv[j].x * wv.x + xv[j].y * wv.y + xv[j].z * wv.z + xv[j].w * wv.w;
      }
    }
    #pragma unroll
    for (int off = 32; off > 0; off >>= 1) {
      #pragma unroll
      for (int e = 0; e < 8; ++e) p[e] += __shfl_down(p[e], off);
    }
    if (lane == 0) {
      float m = p[0];
      #pragma unroll
      for (int e = 1; e < 8; ++e) m = fmaxf(m, p[e]);
      float pr[8], s = 0.f;
      #pragma unroll
      for (int e = 0; e < 8; ++e) { pr[e] = expf(p[e] - m); s += pr[e]; }
      float inv = 1.f / s;
      #pragma unroll
      for (int e = 0; e < 8; ++e) pr[e] *= inv;
      float z = m + logf(s);
      int e0 = 0; float b0 = p[0];
      #pragma unroll
      for (int e = 1; e < 8; ++e) { if (p[e] > b0) { b0 = p[e]; e0 = e; } }
      int e1 = -1; float b1 = -1e30f;
      #pragma unroll
      for (int e = 0; e < 8; ++e) { if (e != e0 && p[e] > b1) { b1 = p[e]; e1 = e; } }
      float p0 = 0.f, p1 = 0.f;
      #pragma unroll
      for (int e = 0; e < 8; ++e) {
        p0 = (e == e0) ? pr[e] : p0;
        p1 = (e == e1) ? pr[e] : p1;
      }
      float gs = p0 + p1 + 1e-9f;
      epack[t] = e0 | (e1 << 16);
      gts[t] = make_float2(p0 / gs, p1 / gs);
      z2_acc += z * z;
      #pragma unroll
      for (int e = 0; e < 8; ++e) {
        imp_acc[e] += pr[e];
        cb_acc[e] += (e == e0) + (e == e1);
        c1_acc[e] += (e == e0);
      }
    }
  }

  __shared__ float simp[4][8];
  __shared__ float sz2[4];
  __shared__ int scb[4][8];
  __shared__ int sc1[4][8];
  if (lane == 0) {
    #pragma unroll
    for (int e = 0; e < 8; ++e) { simp[wid][e] = imp_acc[e]; scb[wid][e] = cb_acc[e]; sc1[wid][e] = c1_acc[e]; }
    sz2[wid] = z2_acc;
  }
  __syncthreads();
  int tid = threadIdx.x;
  if (tid < 8) {
    float s = simp[0][tid] + simp[1][tid] + simp[2][tid] + simp[3][tid];
    int b = scb[0][tid] + scb[1][tid] + scb[2][tid] + scb[3][tid];
    int o = sc1[0][tid] + sc1[1][tid] + sc1[2][tid] + sc1[3][tid];
    atomicAdd(&imp[tid], s);
    atomicAdd(&cntb[tid], b);
    atomicAdd(&cnt1[tid], o);
  } else if (tid == 8) {
    atomicAdd(z2, sz2[0] + sz2[1] + sz2[2] + sz2[3]);
  }
}

// ---------------- offsets + scalar losses ----------------
__global__ void k_finalize(const int* cntb, const int* cnt1, const float* imp,
                           const float* z2, int* offs, float* otail) {
  if (threadIdx.x == 0 && blockIdx.x == 0) {
    int o = 0;
    for (int e = 0; e < 8; ++e) { offs[e] = o; o += cntb[e]; }
    otail[0] = 1e-3f * z2[0] / (float)NT;
    float aux = 0.f;
    for (int e = 0; e < 8; ++e)
      aux += (imp[e] / (float)NT) * ((float)cnt1[e] / (float)NT);
    otail[1] = aux * 8.f;
  }
}

// ---------------- deterministic stable scatter: 1 wave per expert ----------------
__global__ void k_scatter(const int* __restrict__ epack, const float2* __restrict__ gts,
                          const int* __restrict__ offs,
                          int* __restrict__ btok, int* __restrict__ pos) {
  int e = blockIdx.x;
  int lane = threadIdx.x;
  int base = offs[e];
  int run = 0;
  for (int j0 = 0; j0 < 2 * NT; j0 += 64) {
    int j = j0 + lane;
    int t = j >> 1;
    int ep = epack[t];
    int sel = (j & 1) ? (ep >> 16) : (ep & 0xffff);
    bool f = (sel == e);
    unsigned long long m = __ballot(f);
    int rank = __popcll(m & ((1ull << lane) - 1ull));
    if (f) {
      int slot = base + run + rank;
      btok[slot] = t;
      pos[j] = slot;
    }
    run += __popcll(m);
  }
}

// ============ FFN pass 1: Hg = silu(Xg*W1^T) * (Xg*W3^T) ============
// 128x128 tile, BK=32, LDS double-buffered (one barrier per K-step),
// XOR-swizzled staging source + swizzled ds_read (16-way -> 4-way conflicts).
__global__ __launch_bounds__(256) void k_ffn1(
    const unsigned short* __restrict__ xb,
    const unsigned short* __restrict__ w1b,
    const unsigned short* __restrict__ w3b,
    const int* __restrict__ offs, const int* __restrict__ cnts,
    const int* __restrict__ btok,
    unsigned short* __restrict__ hg) {
  int e = blockIdx.z;
  int cnt = cnts[e];
  int m0 = blockIdx.x * 128;          // m fastest: concurrent blocks share W tiles in L2
  if (m0 >= cnt) return;
  int n0 = blockIdx.y * 128;
  int off = offs[e];
  __shared__ __align__(16) short As[2][128 * 32];
  __shared__ __align__(16) short B1s[2][128 * 32];
  __shared__ __align__(16) short B3s[2][128 * 32];
  __shared__ int tok[128];
  int tid = threadIdx.x, lane = tid & 63, wid = tid >> 6;
  if (tid < 128) {
    int r = m0 + tid; if (r > cnt - 1) r = cnt - 1;
    tok[tid] = btok[off + r];
  }
  __syncthreads();

  // staging map: chunk c (=wid*2+{0,1}) covers rows [c*16, c*16+16); HW puts
  // lane l at LDS bytes c*1024 + l*16 -> row c*16 + (l>>2), col elems (l&3)*8.
  // Source col is XOR-pre-swizzled so reads can de-swizzle conflict-free.
  int srl = lane >> 2;                              // row within chunk
  int scol = 8 * ((lane & 3) ^ (srl & 3));          // swizzled source col (elems)
  int c0 = wid * 2, c1 = wid * 2 + 1;
  int ta0 = tok[c0 * 16 + srl];
  int ta1 = tok[c1 * 16 + srl];
  const unsigned short* w1e = w1b + (size_t)e * DF * DM;
  const unsigned short* w3e = w3b + (size_t)e * DF * DM;
  const unsigned short* axp0 = xb + (size_t)ta0 * DM + scol;
  const unsigned short* axp1 = xb + (size_t)ta1 * DM + scol;
  const unsigned short* b1p0 = w1e + (size_t)(n0 + c0 * 16 + srl) * DM + scol;
  const unsigned short* b1p1 = w1e + (size_t)(n0 + c1 * 16 + srl) * DM + scol;
  const unsigned short* b3p0 = w3e + (size_t)(n0 + c0 * 16 + srl) * DM + scol;
  const unsigned short* b3p1 = w3e + (size_t)(n0 + c1 * 16 + srl) * DM + scol;
  int d0 = c0 * 512, d1 = c1 * 512;                 // LDS short-offsets

  auto stage = [&](int h, int kt) {
    int k0 = kt * 32;
    gload16(axp0 + k0, &As[h][d0]);
    gload16(axp1 + k0, &As[h][d1]);
    gload16(b1p0 + k0, &B1s[h][d0]);
    gload16(b1p1 + k0, &B1s[h][d1]);
    gload16(b3p0 + k0, &B3s[h][d0]);
    gload16(b3p1 + k0, &B3s[h][d1]);
  };

  int wm = wid >> 1, wn = wid & 1;
  int fr = lane & 15;
  int fc = 8 * ((lane >> 4) ^ (lane & 3));          // de-swizzled read col (elems)
  f32x4 acc1[4][4] = {};
  f32x4 acc3[4][4] = {};

  stage(0, 0);
  __syncthreads();
  int cur = 0;
  for (int kt = 0; kt < DM / 32; ++kt) {
    if (kt + 1 < DM / 32) stage(cur ^ 1, kt + 1);
    short8 a[4], b1[4], b3[4];
    #pragma unroll
    for (int i = 0; i < 4; ++i) {
      a[i]  = *(const short8*)&As [cur][(wm * 64 + i * 16 + fr) * 32 + fc];
      b1[i] = *(const short8*)&B1s[cur][(wn * 64 + i * 16 + fr) * 32 + fc];
      b3[i] = *(const short8*)&B3s[cur][(wn * 64 + i * 16 + fr) * 32 + fc];
    }
    #pragma unroll
    for (int mi = 0; mi < 4; ++mi) {
      #pragma unroll
      for (int ni = 0; ni < 4; ++ni) {
        acc1[mi][ni] = __builtin_amdgcn_mfma_f32_16x16x32_bf16(a[mi], b1[ni], acc1[mi][ni], 0, 0, 0);
        acc3[mi][ni] = __builtin_amdgcn_mfma_f32_16x16x32_bf16(a[mi], b3[ni], acc3[mi][ni], 0, 0, 0);
      }
    }
    __syncthreads();
    cur ^= 1;
  }

  int cc = lane & 15, r0 = (lane >> 4) * 4;
  #pragma unroll
  for (int mi = 0; mi < 4; ++mi) {
    #pragma unroll
    for (int rg = 0; rg < 4; ++rg) {
      int r = wm * 64 + mi * 16 + r0 + rg;
      int gr = m0 + r;
      if (gr < cnt) {
        unsigned short* hrow = hg + (size_t)(off + gr) * DF + n0;
        #pragma unroll
        for (int ni = 0; ni < 4; ++ni) {
          float a1v = acc1[mi][ni][rg];
          float a3v = acc3[mi][ni][rg];
          float h = (a1v / (1.f + __expf(-a1v))) * a3v;
          hrow[wn * 64 + ni * 16 + cc] = f2bf(h);
        }
      }
    }
  }
}

// ============ FFN pass 2: ys[slot] = Hg[slot] * W2^T ============
__global__ __launch_bounds__(256) void k_ffn2(
    const unsigned short* __restrict__ hg,
    const unsigned short* __restrict__ w2b,
    const int* __restrict__ offs, const int* __restrict__ cnts,
    float* __restrict__ ys) {
  int e = blockIdx.z;
  int cnt = cnts[e];
  int m0 = blockIdx.x * 128;          // m fastest
  if (m0 >= cnt) return;
  int n0 = blockIdx.y * 128;
  int off = offs[e];
  __shared__ __align__(16) short As[2][128 * 32];
  __shared__ __align__(16) short Bs[2][128 * 32];
  int tid = threadIdx.x, lane = tid & 63, wid = tid >> 6;

  int srl = lane >> 2;
  int scol = 8 * ((lane & 3) ^ (srl & 3));
  int c0 = wid * 2, c1 = wid * 2 + 1;
  int ar0 = m0 + c0 * 16 + srl; if (ar0 > cnt - 1) ar0 = cnt - 1;
  int ar1 = m0 + c1 * 16 + srl; if (ar1 > cnt - 1) ar1 = cnt - 1;
  const unsigned short* w2e = w2b + (size_t)e * DM * DF;
  const unsigned short* ap0 = hg + (size_t)(off + ar0) * DF + scol;
  const unsigned short* ap1 = hg + (size_t)(off + ar1) * DF + scol;
  const unsigned short* bp0 = w2e + (size_t)(n0 + c0 * 16 + srl) * DF + scol;
  const unsigned short* bp1 = w2e + (size_t)(n0 + c1 * 16 + srl) * DF + scol;
  int d0 = c0 * 512, d1 = c1 * 512;

  auto stage = [&](int h, int kt) {
    int k0 = kt * 32;
    gload16(ap0 + k0, &As[h][d0]);
    gload16(ap1 + k0, &As[h][d1]);
    gload16(bp0 + k0, &Bs[h][d0]);
    gload16(bp1 + k0, &Bs[h][d1]);
  };

  int wm = wid >> 1, wn = wid & 1;
  int fr = lane & 15;
  int fc = 8 * ((lane >> 4) ^ (lane & 3));
  f32x4 acc[4][4] = {};

  stage(0, 0);
  __syncthreads();
  int cur = 0;
  for (int kt = 0; kt < DF / 32; ++kt) {
    if (kt + 1 < DF / 32) stage(cur ^ 1, kt + 1);
    short8 a[4], b[4];
    #pragma unroll
    for (int i = 0; i < 4; ++i) {
      a[i] = *(const short8*)&As[cur][(wm * 64 + i * 16 + fr) * 32 + fc];
      b[i] = *(const short8*)&Bs[cur][(wn * 64 + i * 16 + fr) * 32 + fc];
    }
    #pragma unroll
    for (int mi = 0; mi < 4; ++mi) {
      #pragma unroll
      for (int ni = 0; ni < 4; ++ni)
        acc[mi][ni] = __builtin_amdgcn_mfma_f32_16x16x32_bf16(a[mi], b[ni], acc[mi][ni], 0, 0, 0);
    }
    __syncthreads();
    cur ^= 1;
  }

  int cc = lane & 15, r0 = (lane >> 4) * 4;
  #pragma unroll
  for (int mi = 0; mi < 4; ++mi) {
    #pragma unroll
    for (int rg = 0; rg < 4; ++rg) {
      int r = wm * 64 + mi * 16 + r0 + rg;
      int gr = m0 + r;
      if (gr < cnt) {
        float* yrow = ys + (size_t)(off + gr) * DM + n0;
        #pragma unroll
        for (int ni = 0; ni < 4; ++ni)
          yrow[wn * 64 + ni * 16 + cc] = acc[mi][ni][rg];
      }
    }
  }
}

// ---------------- gather: out[t] = g0*ys[pos0] + g1*ys[pos1] (full overwrite) ----------------
__global__ void k_gather(const float* __restrict__ ys, const int* __restrict__ pos,
                         const float2* __restrict__ gts, float* __restrict__ out) {
  int idx = blockIdx.x * blockDim.x + threadIdx.x;   // over NT*DM/4
  int t = idx >> 8;
  int d4 = idx & 255;
  float2 g = gts[t];
  const float4* y0 = (const float4*)(ys + (size_t)pos[2 * t] * DM) + d4;
  const float4* y1 = (const float4*)(ys + (size_t)pos[2 * t + 1] * DM) + d4;
  float4 a = *y0, b = *y1, o;
  o.x = g.x * a.x + g.y * b.x;
  o.y = g.x * a.y + g.y * b.y;
  o.z = g.x * a.z + g.y * b.z;
  o.w = g.x * a.w + g.y * b.w;
  ((float4*)out)[idx] = o;
}

// ---------------- workspace layout (bytes) ----------------
// 0        : ctrl (cntb@0, cnt1@32, offs@96, imp@128, z2@160)
// 4096     : epack  int[8192]
// 36864    : gts    float2[8192]
// 102400   : btok   int[16384]
// 167936   : pos    int[16384]
// 233472   : x_bf16   (16.78 MB)
// 17010688 : W1_bf16  (33.55 MB)   <- ys fp32 (67.1 MB) aliases W1+W3 after ffn1
// 50565120 : W3_bf16  (33.55 MB)
// 84119552 : W2_bf16  (33.55 MB)
// 117673984: Hg bf16  (67.11 MB)   -> total 184782848 B (~176 MiB)

extern "C" void kernel_launch(void* const* d_in, const int* in_sizes, int n_in,
                              void* d_out, int out_size, void* d_ws, size_t ws_size,
                              hipStream_t stream) {
  const float* x  = (const float*)d_in[0];
  const float* wr = (const float*)d_in[1];
  const float* w1 = (const float*)d_in[2];
  const float* w3 = (const float*)d_in[3];
  const float* w2 = (const float*)d_in[4];
  float* out = (float*)d_out;

  uint8_t* ws = (uint8_t*)d_ws;
  int*    cntb   = (int*)(ws + 0);
  int*    cnt1   = (int*)(ws + 32);
  int*    offs   = (int*)(ws + 96);
  float*  imp    = (float*)(ws + 128);
  float*  z2     = (float*)(ws + 160);
  int*    epack  = (int*)(ws + 4096);
  float2* gts    = (float2*)(ws + 36864);
  int*    btok   = (int*)(ws + 102400);
  int*    pos    = (int*)(ws + 167936);
  unsigned short* xbf  = (unsigned short*)(ws + 233472);
  unsigned short* w1bf = (unsigned short*)(ws + 17010688);
  unsigned short* w3bf = (unsigned short*)(ws + 50565120);
  unsigned short* w2bf = (unsigned short*)(ws + 84119552);
  unsigned short* hg   = (unsigned short*)(ws + 117673984);
  float*          ysb  = (float*)(ws + 17010688);   // aliases w1bf+w3bf (dead after ffn1)

  hipMemsetAsync(ws, 0, 4096, stream);

  k_cvt3<<<dim3(2048, 3), 256, 0, stream>>>(
      (const float4*)w1, (const float4*)w3, (const float4*)w2,
      (ushort4*)w1bf, (ushort4*)w3bf, (ushort4*)w2bf, 8 * DF * DM / 4);

  k_router<<<RT_BLOCKS, 256, 0, stream>>>(x, wr, cntb, cnt1, imp, z2, epack, gts, xbf);
  k_finalize<<<1, 64, 0, stream>>>(cntb, cnt1, imp, z2, offs, out + (size_t)NT * DM);
  k_scatter<<<8, 64, 0, stream>>>(epack, gts, offs, btok, pos);

  k_ffn1<<<dim3(64, 16, 8), 256, 0, stream>>>(xbf, w1bf, w3bf, offs, cntb, btok, hg);
  k_ffn2<<<dim3(64, 8, 8), 256, 0, stream>>>(hg, w2bf, offs, cntb, ysb);
  k_gather<<<NT * DM / 4 / 256, 256, 0, stream>>>(ysb, pos, gts, out);
}

// Round 5
// 562.328 us; speedup vs baseline: 1.4187x; 1.4187x over previous
//
#include <hip/hip_runtime.h>
#include <stdint.h>

#define NT 8192      // tokens
#define DM 1024      // d_model
#define DF 2048      // d_ff
#define RT_BLOCKS 256

typedef __attribute__((ext_vector_type(8))) short short8;
typedef __attribute__((ext_vector_type(4))) float f32x4;

__device__ __forceinline__ unsigned short f2bf(float f) {
  uint32_t x = __float_as_uint(f);
  return (unsigned short)((x + 0x7fffu + ((x >> 16) & 1u)) >> 16);
}

__device__ __forceinline__ void gload16(const void* g, void* l) {
  __builtin_amdgcn_global_load_lds(
      (const __attribute__((address_space(1))) uint32_t*)g,
      (__attribute__((address_space(3))) uint32_t*)l, 16, 0, 0);
}

// ---------------- fp32 -> bf16 converts ----------------
// y=0: W1 -> w13 rows 2f   (interleaved)
// y=1: W3 -> w13 rows 2f+1
// y=2: W2 -> w2bf (plain)
__global__ void k_cvtw(const float4* __restrict__ w1, const float4* __restrict__ w3,
                       const float4* __restrict__ w2,
                       ushort4* __restrict__ w13, ushort4* __restrict__ w2bf) {
  int s = blockIdx.y;
  const float4* src = (s == 0) ? w1 : (s == 1) ? w3 : w2;
  int n4 = 8 * DF * DM / 4;
  int i = blockIdx.x * blockDim.x + threadIdx.x;
  int st = gridDim.x * blockDim.x;
  for (; i < n4; i += st) {
    float4 v = src[i];
    ushort4 o;
    o.x = f2bf(v.x); o.y = f2bf(v.y); o.z = f2bf(v.z); o.w = f2bf(v.w);
    if (s == 2) {
      w2bf[i] = o;
    } else {
      int e = i >> 19;               // DF*DM/4 = 2^19
      int rem = i & ((1 << 19) - 1);
      int f = rem >> 8;              // DM/4 = 256
      int k4 = rem & 255;
      w13[((size_t)e << 20) + (size_t)(2 * f + s) * 256 + k4] = o;
    }
  }
}

// ---------------- router: logits, softmax, top2, losses; also emits x in bf16 ----------------
__global__ void k_router(const float* __restrict__ x, const float* __restrict__ wr,
                         int* cntb, int* cnt1, float* imp, float* z2,
                         int* epack, float2* gts, unsigned short* __restrict__ xbf) {
  int lane = threadIdx.x & 63;
  int wid = threadIdx.x >> 6;
  const float4* w4 = (const float4*)wr;

  float imp_acc[8] = {0.f, 0.f, 0.f, 0.f, 0.f, 0.f, 0.f, 0.f};
  float z2_acc = 0.f;
  int cb_acc[8] = {0, 0, 0, 0, 0, 0, 0, 0};
  int c1_acc[8] = {0, 0, 0, 0, 0, 0, 0, 0};

  for (int t = blockIdx.x * 4 + wid; t < NT; t += RT_BLOCKS * 4) {
    const float4* x4 = (const float4*)(x + (size_t)t * DM);
    ushort4* xb4 = (ushort4*)(xbf + (size_t)t * DM);
    float4 xv[4];
    #pragma unroll
    for (int j = 0; j < 4; ++j) {
      xv[j] = x4[lane + 64 * j];
      ushort4 o;
      o.x = f2bf(xv[j].x); o.y = f2bf(xv[j].y); o.z = f2bf(xv[j].z); o.w = f2bf(xv[j].w);
      xb4[lane + 64 * j] = o;
    }
    float p[8];
    #pragma unroll
    for (int e = 0; e < 8; ++e) p[e] = 0.f;
    #pragma unroll
    for (int j = 0; j < 4; ++j) {
      #pragma unroll
      for (int e = 0; e < 8; ++e) {
        float4 wv = w4[e * 256 + lane + 64 * j];
        p[e] += xv[j].x * wv.x + xv[j].y * wv.y + xv[j].z * wv.z + xv[j].w * wv.w;
      }
    }
    #pragma unroll
    for (int off = 32; off > 0; off >>= 1) {
      #pragma unroll
      for (int e = 0; e < 8; ++e) p[e] += __shfl_down(p[e], off);
    }
    if (lane == 0) {
      float m = p[0];
      #pragma unroll
      for (int e = 1; e < 8; ++e) m = fmaxf(m, p[e]);
      float pr[8], s = 0.f;
      #pragma unroll
      for (int e = 0; e < 8; ++e) { pr[e] = expf(p[e] - m); s += pr[e]; }
      float inv = 1.f / s;
      #pragma unroll
      for (int e = 0; e < 8; ++e) pr[e] *= inv;
      float z = m + logf(s);
      int e0 = 0; float b0 = p[0];
      #pragma unroll
      for (int e = 1; e < 8; ++e) { if (p[e] > b0) { b0 = p[e]; e0 = e; } }
      int e1 = -1; float b1 = -1e30f;
      #pragma unroll
      for (int e = 0; e < 8; ++e) { if (e != e0 && p[e] > b1) { b1 = p[e]; e1 = e; } }
      float p0 = 0.f, p1 = 0.f;
      #pragma unroll
      for (int e = 0; e < 8; ++e) {
        p0 = (e == e0) ? pr[e] : p0;
        p1 = (e == e1) ? pr[e] : p1;
      }
      float gs = p0 + p1 + 1e-9f;
      epack[t] = e0 | (e1 << 16);
      gts[t] = make_float2(p0 / gs, p1 / gs);
      z2_acc += z * z;
      #pragma unroll
      for (int e = 0; e < 8; ++e) {
        imp_acc[e] += pr[e];
        cb_acc[e] += (e == e0) + (e == e1);
        c1_acc[e] += (e == e0);
      }
    }
  }

  __shared__ float simp[4][8];
  __shared__ float sz2[4];
  __shared__ int scb[4][8];
  __shared__ int sc1[4][8];
  if (lane == 0) {
    #pragma unroll
    for (int e = 0; e < 8; ++e) { simp[wid][e] = imp_acc[e]; scb[wid][e] = cb_acc[e]; sc1[wid][e] = c1_acc[e]; }
    sz2[wid] = z2_acc;
  }
  __syncthreads();
  int tid = threadIdx.x;
  if (tid < 8) {
    float s = simp[0][tid] + simp[1][tid] + simp[2][tid] + simp[3][tid];
    int b = scb[0][tid] + scb[1][tid] + scb[2][tid] + scb[3][tid];
    int o = sc1[0][tid] + sc1[1][tid] + sc1[2][tid] + sc1[3][tid];
    atomicAdd(&imp[tid], s);
    atomicAdd(&cntb[tid], b);
    atomicAdd(&cnt1[tid], o);
  } else if (tid == 8) {
    atomicAdd(z2, sz2[0] + sz2[1] + sz2[2] + sz2[3]);
  }
}

// ---------------- offsets + scalar losses ----------------
__global__ void k_finalize(const int* cntb, const int* cnt1, const float* imp,
                           const float* z2, int* offs, float* otail) {
  if (threadIdx.x == 0 && blockIdx.x == 0) {
    int o = 0;
    for (int e = 0; e < 8; ++e) { offs[e] = o; o += cntb[e]; }
    otail[0] = 1e-3f * z2[0] / (float)NT;
    float aux = 0.f;
    for (int e = 0; e < 8; ++e)
      aux += (imp[e] / (float)NT) * ((float)cnt1[e] / (float)NT);
    otail[1] = aux * 8.f;
  }
}

// ---------------- deterministic stable scatter: 1 wave per expert ----------------
__global__ void k_scatter(const int* __restrict__ epack, const float2* __restrict__ gts,
                          const int* __restrict__ offs,
                          int* __restrict__ btok, int* __restrict__ pos) {
  int e = blockIdx.x;
  int lane = threadIdx.x;
  int base = offs[e];
  int run = 0;
  for (int j0 = 0; j0 < 2 * NT; j0 += 64) {
    int j = j0 + lane;
    int t = j >> 1;
    int ep = epack[t];
    int sel = (j & 1) ? (ep >> 16) : (ep & 0xffff);
    bool f = (sel == e);
    unsigned long long m = __ballot(f);
    int rank = __popcll(m & ((1ull << lane) - 1ull));
    if (f) {
      int slot = base + run + rank;
      btok[slot] = t;
      pos[j] = slot;
    }
    run += __popcll(m);
  }
}

// ============ FFN pass 1: Hg = silu(Xg*W1^T)*(Xg*W3^T), W13 interleaved ============
// 256x256 tile, BK=64, 512 thr (8 waves 2Mx4N), dbuf LDS 128KB,
// G^(row&7) swizzle (2-way = free) via pre-swizzled global source.
__global__ __launch_bounds__(512, 2) void k_ffn1(
    const unsigned short* __restrict__ xb,
    const unsigned short* __restrict__ w13,
    const int* __restrict__ offs, const int* __restrict__ cnts,
    const int* __restrict__ btok,
    unsigned short* __restrict__ hg) {
  int e = blockIdx.z;
  int cnt = cnts[e];
  int m0 = blockIdx.y * 256;
  if (m0 >= cnt) return;
  int n0 = blockIdx.x * 256;            // over interleaved N = 2*DF = 4096
  int off = offs[e];
  __shared__ __align__(16) short As[2][256 * 64];
  __shared__ __align__(16) short Bs[2][256 * 64];
  __shared__ int tok[256];
  int tid = threadIdx.x, lane = tid & 63, wid = tid >> 6;
  if (tid < 256) {
    int r = m0 + tid; if (r > cnt - 1) r = cnt - 1;
    tok[tid] = btok[off + r];
  }
  __syncthreads();

  // staging: 32 chunks of 8 rows; chunk = wid*4+i; lane l -> row rin=l>>3,
  // LDS group l&7; source col pre-swizzled by row&7 (involution).
  int rin = lane >> 3;
  int scol = (((lane & 7) ^ rin)) * 8;  // elems
  const unsigned short* w13e = w13 + ((size_t)e << 22);  // 2*DF*DM = 2^22
  const unsigned short* asrc[4];
  const unsigned short* bsrc[4];
  int dofs[4];
  #pragma unroll
  for (int i = 0; i < 4; ++i) {
    int ch = wid * 4 + i;
    int rr = ch * 8 + rin;
    asrc[i] = xb + (size_t)tok[rr] * DM + scol;
    bsrc[i] = w13e + (size_t)(n0 + rr) * DM + scol;
    dofs[i] = ch * 512;                // shorts (chunk*1024B)
  }

  int wm = wid >> 2, wn = wid & 3;
  int g = lane >> 4;
  int l7 = lane & 7;
  int fr = lane & 15;
  f32x4 acc[8][4] = {};

  // prologue
  #pragma unroll
  for (int i = 0; i < 4; ++i) {
    gload16(asrc[i], &As[0][dofs[i]]);
    gload16(bsrc[i], &Bs[0][dofs[i]]);
  }
  __syncthreads();

  int cur = 0;
  const int NK = DM / 64;
  for (int kt = 0; kt < NK; ++kt) {
    if (kt + 1 < NK) {
      int k0 = (kt + 1) * 64;
      #pragma unroll
      for (int i = 0; i < 4; ++i) {
        gload16(asrc[i] + k0, &As[cur ^ 1][dofs[i]]);
        gload16(bsrc[i] + k0, &Bs[cur ^ 1][dofs[i]]);
      }
    }
    #pragma unroll
    for (int kk = 0; kk < 2; ++kk) {
      int G = kk * 4 + g;
      short8 a[8], b[4];
      #pragma unroll
      for (int mi = 0; mi < 8; ++mi) {
        int r = wm * 128 + mi * 16 + fr;
        a[mi] = *(const short8*)&As[cur][r * 64 + ((G ^ l7) * 8)];
      }
      #pragma unroll
      for (int ni = 0; ni < 4; ++ni) {
        int r = wn * 64 + ni * 16 + fr;
        b[ni] = *(const short8*)&Bs[cur][r * 64 + ((G ^ l7) * 8)];
      }
      #pragma unroll
      for (int mi = 0; mi < 8; ++mi) {
        #pragma unroll
        for (int ni = 0; ni < 4; ++ni)
          acc[mi][ni] = __builtin_amdgcn_mfma_f32_16x16x32_bf16(a[mi], b[ni], acc[mi][ni], 0, 0, 0);
      }
    }
    __syncthreads();
    cur ^= 1;
  }

  // epilogue: pair even/odd C columns (W1/W3) via shfl_xor(1), silu*mul, store bf16
  int c = lane & 15, r4 = (lane >> 4) * 4;
  bool evenc = ((c & 1) == 0);
  #pragma unroll
  for (int mi = 0; mi < 8; ++mi) {
    #pragma unroll
    for (int rg = 0; rg < 4; ++rg) {
      int gr = m0 + wm * 128 + mi * 16 + r4 + rg;
      #pragma unroll
      for (int ni = 0; ni < 4; ++ni) {
        float a1 = acc[mi][ni][rg];
        float a3 = __shfl_xor(a1, 1);
        if (evenc && gr < cnt) {
          int f = (n0 + wn * 64 + ni * 16 + c) >> 1;
          float h = (a1 / (1.f + __expf(-a1))) * a3;
          hg[(size_t)(off + gr) * DF + f] = f2bf(h);
        }
      }
    }
  }
}

// ============ FFN pass 2: ys[slot] = Hg[slot] * W2^T ============
__global__ __launch_bounds__(512, 2) void k_ffn2(
    const unsigned short* __restrict__ hg,
    const unsigned short* __restrict__ w2b,
    const int* __restrict__ offs, const int* __restrict__ cnts,
    float* __restrict__ ys) {
  int e = blockIdx.z;
  int cnt = cnts[e];
  int m0 = blockIdx.y * 256;
  if (m0 >= cnt) return;
  int n0 = blockIdx.x * 256;            // over DM = 1024
  int off = offs[e];
  __shared__ __align__(16) short As[2][256 * 64];
  __shared__ __align__(16) short Bs[2][256 * 64];
  int tid = threadIdx.x, lane = tid & 63, wid = tid >> 6;

  int rin = lane >> 3;
  int scol = (((lane & 7) ^ rin)) * 8;
  const unsigned short* w2e = w2b + ((size_t)e << 21);   // DM*DF = 2^21
  const unsigned short* asrc[4];
  const unsigned short* bsrc[4];
  int dofs[4];
  #pragma unroll
  for (int i = 0; i < 4; ++i) {
    int ch = wid * 4 + i;
    int rr = ch * 8 + rin;
    int ar = m0 + rr; if (ar > cnt - 1) ar = cnt - 1;
    asrc[i] = hg + (size_t)(off + ar) * DF + scol;
    bsrc[i] = w2e + (size_t)(n0 + rr) * DF + scol;
    dofs[i] = ch * 512;
  }

  int wm = wid >> 2, wn = wid & 3;
  int g = lane >> 4;
  int l7 = lane & 7;
  int fr = lane & 15;
  f32x4 acc[8][4] = {};

  #pragma unroll
  for (int i = 0; i < 4; ++i) {
    gload16(asrc[i], &As[0][dofs[i]]);
    gload16(bsrc[i], &Bs[0][dofs[i]]);
  }
  __syncthreads();

  int cur = 0;
  const int NK = DF / 64;
  for (int kt = 0; kt < NK; ++kt) {
    if (kt + 1 < NK) {
      int k0 = (kt + 1) * 64;
      #pragma unroll
      for (int i = 0; i < 4; ++i) {
        gload16(asrc[i] + k0, &As[cur ^ 1][dofs[i]]);
        gload16(bsrc[i] + k0, &Bs[cur ^ 1][dofs[i]]);
      }
    }
    #pragma unroll
    for (int kk = 0; kk < 2; ++kk) {
      int G = kk * 4 + g;
      short8 a[8], b[4];
      #pragma unroll
      for (int mi = 0; mi < 8; ++mi) {
        int r = wm * 128 + mi * 16 + fr;
        a[mi] = *(const short8*)&As[cur][r * 64 + ((G ^ l7) * 8)];
      }
      #pragma unroll
      for (int ni = 0; ni < 4; ++ni) {
        int r = wn * 64 + ni * 16 + fr;
        b[ni] = *(const short8*)&Bs[cur][r * 64 + ((G ^ l7) * 8)];
      }
      #pragma unroll
      for (int mi = 0; mi < 8; ++mi) {
        #pragma unroll
        for (int ni = 0; ni < 4; ++ni)
          acc[mi][ni] = __builtin_amdgcn_mfma_f32_16x16x32_bf16(a[mi], b[ni], acc[mi][ni], 0, 0, 0);
      }
    }
    __syncthreads();
    cur ^= 1;
  }

  int c = lane & 15, r4 = (lane >> 4) * 4;
  #pragma unroll
  for (int mi = 0; mi < 8; ++mi) {
    #pragma unroll
    for (int rg = 0; rg < 4; ++rg) {
      int gr = m0 + wm * 128 + mi * 16 + r4 + rg;
      if (gr < cnt) {
        float* yrow = ys + (size_t)(off + gr) * DM + n0;
        #pragma unroll
        for (int ni = 0; ni < 4; ++ni)
          yrow[wn * 64 + ni * 16 + c] = acc[mi][ni][rg];
      }
    }
  }
}

// ---------------- gather: out[t] = g0*ys[pos0] + g1*ys[pos1] (full overwrite) ----------------
__global__ void k_gather(const float* __restrict__ ys, const int* __restrict__ pos,
                         const float2* __restrict__ gts, float* __restrict__ out) {
  int idx = blockIdx.x * blockDim.x + threadIdx.x;   // over NT*DM/4
  int t = idx >> 8;
  int d4 = idx & 255;
  float2 g = gts[t];
  const float4* y0 = (const float4*)(ys + (size_t)pos[2 * t] * DM) + d4;
  const float4* y1 = (const float4*)(ys + (size_t)pos[2 * t + 1] * DM) + d4;
  float4 a = *y0, b = *y1, o;
  o.x = g.x * a.x + g.y * b.x;
  o.y = g.x * a.y + g.y * b.y;
  o.z = g.x * a.z + g.y * b.z;
  o.w = g.x * a.w + g.y * b.w;
  ((float4*)out)[idx] = o;
}

// ---------------- workspace layout (bytes) ----------------
// 0        : ctrl (cntb@0, cnt1@32, offs@96, imp@128, z2@160)
// 4096     : epack  int[8192]
// 36864    : gts    float2[8192]
// 102400   : btok   int[16384]
// 167936   : pos    int[16384]
// 233472   : x_bf16   (16.78 MB)
// 17010688 : W13_bf16 interleaved (67.11 MB)  <- ys fp32 (67.1 MB) aliases after ffn1
// 84119552 : W2_bf16  (33.55 MB)
// 117673984: Hg bf16  (67.11 MB)   -> total 184782848 B (~176 MiB)

extern "C" void kernel_launch(void* const* d_in, const int* in_sizes, int n_in,
                              void* d_out, int out_size, void* d_ws, size_t ws_size,
                              hipStream_t stream) {
  const float* x  = (const float*)d_in[0];
  const float* wr = (const float*)d_in[1];
  const float* w1 = (const float*)d_in[2];
  const float* w3 = (const float*)d_in[3];
  const float* w2 = (const float*)d_in[4];
  float* out = (float*)d_out;

  uint8_t* ws = (uint8_t*)d_ws;
  int*    cntb   = (int*)(ws + 0);
  int*    cnt1   = (int*)(ws + 32);
  int*    offs   = (int*)(ws + 96);
  float*  imp    = (float*)(ws + 128);
  float*  z2     = (float*)(ws + 160);
  int*    epack  = (int*)(ws + 4096);
  float2* gts    = (float2*)(ws + 36864);
  int*    btok   = (int*)(ws + 102400);
  int*    pos    = (int*)(ws + 167936);
  unsigned short* xbf  = (unsigned short*)(ws + 233472);
  unsigned short* w13  = (unsigned short*)(ws + 17010688);
  unsigned short* w2bf = (unsigned short*)(ws + 84119552);
  unsigned short* hg   = (unsigned short*)(ws + 117673984);
  float*          ysb  = (float*)(ws + 17010688);   // aliases w13 (dead after ffn1)

  hipMemsetAsync(ws, 0, 4096, stream);

  k_cvtw<<<dim3(2048, 3), 256, 0, stream>>>(
      (const float4*)w1, (const float4*)w3, (const float4*)w2,
      (ushort4*)w13, (ushort4*)w2bf);

  k_router<<<RT_BLOCKS, 256, 0, stream>>>(x, wr, cntb, cnt1, imp, z2, epack, gts, xbf);
  k_finalize<<<1, 64, 0, stream>>>(cntb, cnt1, imp, z2, offs, out + (size_t)NT * DM);
  k_scatter<<<8, 64, 0, stream>>>(epack, gts, offs, btok, pos);

  k_ffn1<<<dim3(16, 64, 8), 512, 0, stream>>>(xbf, w13, offs, cntb, btok, hg);
  k_ffn2<<<dim3(4, 64, 8), 512, 0, stream>>>(hg, w2bf, offs, cntb, ysb);
  k_gather<<<NT * DM / 4 / 256, 256, 0, stream>>>(ysb, pos, gts, out);
}

// Round 6
// 549.273 us; speedup vs baseline: 1.4524x; 1.0238x over previous
//
#include <hip/hip_runtime.h>
#include <stdint.h>

#define NT 8192      // tokens
#define DM 1024      // d_model
#define DF 2048      // d_ff
#define RT_BLOCKS 256

typedef __attribute__((ext_vector_type(8))) short short8;
typedef __attribute__((ext_vector_type(4))) float f32x4;
typedef unsigned short us;

__device__ __forceinline__ us f2bf(float f) {
  uint32_t x = __float_as_uint(f);
  return (us)((x + 0x7fffu + ((x >> 16) & 1u)) >> 16);
}

__device__ __forceinline__ void gload16(const void* g, void* l) {
  __builtin_amdgcn_global_load_lds(
      (const __attribute__((address_space(1))) uint32_t*)g,
      (__attribute__((address_space(3))) uint32_t*)l, 16, 0, 0);
}

// ---------------- fp32 -> bf16 converts ----------------
__global__ void k_cvtw(const float4* __restrict__ w1, const float4* __restrict__ w3,
                       const float4* __restrict__ w2,
                       ushort4* __restrict__ w13, ushort4* __restrict__ w2bf) {
  int s = blockIdx.y;
  const float4* src = (s == 0) ? w1 : (s == 1) ? w3 : w2;
  int n4 = 8 * DF * DM / 4;
  int i = blockIdx.x * blockDim.x + threadIdx.x;
  int st = gridDim.x * blockDim.x;
  for (; i < n4; i += st) {
    float4 v = src[i];
    ushort4 o;
    o.x = f2bf(v.x); o.y = f2bf(v.y); o.z = f2bf(v.z); o.w = f2bf(v.w);
    if (s == 2) {
      w2bf[i] = o;
    } else {
      int e = i >> 19;
      int rem = i & ((1 << 19) - 1);
      int f = rem >> 8;
      int k4 = rem & 255;
      w13[((size_t)e << 20) + (size_t)(2 * f + s) * 256 + k4] = o;
    }
  }
}

// ---------------- router ----------------
__global__ void k_router(const float* __restrict__ x, const float* __restrict__ wr,
                         int* cntb, int* cnt1, float* imp, float* z2,
                         int* epack, float2* gts, us* __restrict__ xbf) {
  int lane = threadIdx.x & 63;
  int wid = threadIdx.x >> 6;
  const float4* w4 = (const float4*)wr;

  float imp_acc[8] = {0.f, 0.f, 0.f, 0.f, 0.f, 0.f, 0.f, 0.f};
  float z2_acc = 0.f;
  int cb_acc[8] = {0, 0, 0, 0, 0, 0, 0, 0};
  int c1_acc[8] = {0, 0, 0, 0, 0, 0, 0, 0};

  for (int t = blockIdx.x * 4 + wid; t < NT; t += RT_BLOCKS * 4) {
    const float4* x4 = (const float4*)(x + (size_t)t * DM);
    ushort4* xb4 = (ushort4*)(xbf + (size_t)t * DM);
    float4 xv[4];
    #pragma unroll
    for (int j = 0; j < 4; ++j) {
      xv[j] = x4[lane + 64 * j];
      ushort4 o;
      o.x = f2bf(xv[j].x); o.y = f2bf(xv[j].y); o.z = f2bf(xv[j].z); o.w = f2bf(xv[j].w);
      xb4[lane + 64 * j] = o;
    }
    float p[8];
    #pragma unroll
    for (int e = 0; e < 8; ++e) p[e] = 0.f;
    #pragma unroll
    for (int j = 0; j < 4; ++j) {
      #pragma unroll
      for (int e = 0; e < 8; ++e) {
        float4 wv = w4[e * 256 + lane + 64 * j];
        p[e] += xv[j].x * wv.x + xv[j].y * wv.y + xv[j].z * wv.z + xv[j].w * wv.w;
      }
    }
    #pragma unroll
    for (int off = 32; off > 0; off >>= 1) {
      #pragma unroll
      for (int e = 0; e < 8; ++e) p[e] += __shfl_down(p[e], off);
    }
    if (lane == 0) {
      float m = p[0];
      #pragma unroll
      for (int e = 1; e < 8; ++e) m = fmaxf(m, p[e]);
      float pr[8], s = 0.f;
      #pragma unroll
      for (int e = 0; e < 8; ++e) { pr[e] = expf(p[e] - m); s += pr[e]; }
      float inv = 1.f / s;
      #pragma unroll
      for (int e = 0; e < 8; ++e) pr[e] *= inv;
      float z = m + logf(s);
      int e0 = 0; float b0 = p[0];
      #pragma unroll
      for (int e = 1; e < 8; ++e) { if (p[e] > b0) { b0 = p[e]; e0 = e; } }
      int e1 = -1; float b1 = -1e30f;
      #pragma unroll
      for (int e = 0; e < 8; ++e) { if (e != e0 && p[e] > b1) { b1 = p[e]; e1 = e; } }
      float p0 = 0.f, p1 = 0.f;
      #pragma unroll
      for (int e = 0; e < 8; ++e) {
        p0 = (e == e0) ? pr[e] : p0;
        p1 = (e == e1) ? pr[e] : p1;
      }
      float gs = p0 + p1 + 1e-9f;
      epack[t] = e0 | (e1 << 16);
      gts[t] = make_float2(p0 / gs, p1 / gs);
      z2_acc += z * z;
      #pragma unroll
      for (int e = 0; e < 8; ++e) {
        imp_acc[e] += pr[e];
        cb_acc[e] += (e == e0) + (e == e1);
        c1_acc[e] += (e == e0);
      }
    }
  }

  __shared__ float simp[4][8];
  __shared__ float sz2[4];
  __shared__ int scb[4][8];
  __shared__ int sc1[4][8];
  if (lane == 0) {
    #pragma unroll
    for (int e = 0; e < 8; ++e) { simp[wid][e] = imp_acc[e]; scb[wid][e] = cb_acc[e]; sc1[wid][e] = c1_acc[e]; }
    sz2[wid] = z2_acc;
  }
  __syncthreads();
  int tid = threadIdx.x;
  if (tid < 8) {
    float s = simp[0][tid] + simp[1][tid] + simp[2][tid] + simp[3][tid];
    int b = scb[0][tid] + scb[1][tid] + scb[2][tid] + scb[3][tid];
    int o = sc1[0][tid] + sc1[1][tid] + sc1[2][tid] + sc1[3][tid];
    atomicAdd(&imp[tid], s);
    atomicAdd(&cntb[tid], b);
    atomicAdd(&cnt1[tid], o);
  } else if (tid == 8) {
    atomicAdd(z2, sz2[0] + sz2[1] + sz2[2] + sz2[3]);
  }
}

// ---------------- offsets + scalar losses ----------------
__global__ void k_finalize(const int* cntb, const int* cnt1, const float* imp,
                           const float* z2, int* offs, float* otail) {
  if (threadIdx.x == 0 && blockIdx.x == 0) {
    int o = 0;
    for (int e = 0; e < 8; ++e) { offs[e] = o; o += cntb[e]; }
    otail[0] = 1e-3f * z2[0] / (float)NT;
    float aux = 0.f;
    for (int e = 0; e < 8; ++e)
      aux += (imp[e] / (float)NT) * ((float)cnt1[e] / (float)NT);
    otail[1] = aux * 8.f;
  }
}

// ---------------- deterministic stable scatter ----------------
__global__ void k_scatter(const int* __restrict__ epack, const float2* __restrict__ gts,
                          const int* __restrict__ offs,
                          int* __restrict__ btok, int* __restrict__ pos) {
  int e = blockIdx.x;
  int lane = threadIdx.x;
  int base = offs[e];
  int run = 0;
  for (int j0 = 0; j0 < 2 * NT; j0 += 64) {
    int j = j0 + lane;
    int t = j >> 1;
    int ep = epack[t];
    int sel = (j & 1) ? (ep >> 16) : (ep & 0xffff);
    bool f = (sel == e);
    unsigned long long m = __ballot(f);
    int rank = __popcll(m & ((1ull << lane) - 1ull));
    if (f) {
      int slot = base + run + rank;
      btok[slot] = t;
      pos[j] = slot;
    }
    run += __popcll(m);
  }
}

// ============================================================================
// Phase-pipelined grouped GEMM core (T3+T4+T5):
//  - 256x256 tile, BK=64 as 2 K-halves (32 cols) per tensor per tile.
//  - Ring of 4 K-half slots per tensor (= 2 tiles). Staging of tile t+1's
//    4 halves is spread over tile t's 4 phases (A-kk0, B-kk0, A-kk1, B-kk1).
//  - Waits are s_waitcnt vmcnt(4) twice per tile (before kk0 reads, before
//    kk1 reads) -- never 0: the 4 newest loads stay in flight across barriers.
//  - 2 raw s_barriers per tile. Ring safety: slot staged at t.phX was last
//    read at tile t-1 phase <=X; both barriers of tile t precede the issue.
//  - Slot layout: 128 physical rows x 128B; cell pc=(prow*8+pos), logical
//    (row,g): prow=row>>1, pos=((row&1)<<2|g)^(prow&7)  (2-way banks = free).
//    gload_lds dest linear in pc; source address carries the inverse swizzle.
// ============================================================================

#define FFN_PHASE_READS(slot, mi0, a, b, DOB)                                   \
  if (DOB) {                                                                    \
    _Pragma("unroll")                                                           \
    for (int ni = 0; ni < 4; ++ni)                                              \
      b[ni] = *(const short8*)&Bs[slot][boff + ni * 512];                       \
  }                                                                             \
  _Pragma("unroll")                                                             \
  for (int mi = 0; mi < 4; ++mi)                                                \
    a[mi] = *(const short8*)&As[slot][aoff + (mi0 + mi) * 512];

#define FFN_PHASE_MFMA(mi0, a, b)                                               \
  __builtin_amdgcn_s_setprio(1);                                                \
  _Pragma("unroll")                                                             \
  for (int mi = 0; mi < 4; ++mi) {                                              \
    _Pragma("unroll")                                                           \
    for (int ni = 0; ni < 4; ++ni)                                              \
      acc[mi0 + mi][ni] =                                                       \
          __builtin_amdgcn_mfma_f32_16x16x32_bf16(a[mi], b[ni],                 \
                                                  acc[mi0 + mi][ni], 0, 0, 0);  \
  }                                                                             \
  __builtin_amdgcn_s_setprio(0);

// ---------------- FFN pass 1 ----------------
__global__ __launch_bounds__(512, 2) void k_ffn1(
    const us* __restrict__ xb, const us* __restrict__ w13,
    const int* __restrict__ offs, const int* __restrict__ cnts,
    const int* __restrict__ btok, us* __restrict__ hg) {
  int e = blockIdx.z;
  int cnt = cnts[e];
  int m0 = blockIdx.y * 256;
  if (m0 >= cnt) return;
  int n0 = blockIdx.x * 256;
  int off = offs[e];
  __shared__ __align__(16) short As[4][8192];
  __shared__ __align__(16) short Bs[4][8192];
  __shared__ int tok[256];
  int tid = threadIdx.x, lane = tid & 63, wid = tid >> 6;
  if (tid < 256) {
    int r = m0 + tid; if (r > cnt - 1) r = cnt - 1;
    tok[tid] = btok[off + r];
  }
  __syncthreads();

  // ---- staging source precompute (per thread, 2 loads per half) ----
  int posun = (lane & 7) ^ ((lane >> 3) & 7);
  int rl0 = wid * 32 + ((lane >> 3) << 1) + (posun >> 2);  // j=0 logical row
  int rl1 = rl0 + 16;                                      // j=1
  int gcol = (posun & 3) * 8;                              // logical K-group
  const us* w13e = w13 + ((size_t)e << 22);
  const us* a0 = xb + (size_t)tok[rl0] * DM + gcol;
  const us* a1 = xb + (size_t)tok[rl1] * DM + gcol;
  const us* b0 = w13e + (size_t)(n0 + rl0) * DM + gcol;
  const us* b1 = w13e + (size_t)(n0 + rl1) * DM + gcol;
  int dst0 = wid * 1024, dst1 = wid * 1024 + 512;          // shorts

  auto stageA = [&](int ko, int slot) {
    gload16(a0 + ko, &As[slot][dst0]);
    gload16(a1 + ko, &As[slot][dst1]);
  };
  auto stageB = [&](int ko, int slot) {
    gload16(b0 + ko, &Bs[slot][dst0]);
    gload16(b1 + ko, &Bs[slot][dst1]);
  };

  // ---- fragment read offsets ----
  int wm = wid >> 2, wn = wid & 3;
  int fr = lane & 15, glog = lane >> 4;
  int pos = (((fr & 1) << 2) | glog) ^ ((fr >> 1) & 7);
  int aoff = (wm * 64 + (fr >> 1)) * 64 + pos * 8;
  int boff = (wn * 32 + (fr >> 1)) * 64 + pos * 8;
  f32x4 acc[8][4] = {};

  // ---- prologue: tile 0 halves in order A0,B0,A1,B1 ----
  stageA(0, 0); stageB(0, 0); stageA(32, 1); stageB(32, 1);

  const int NK = DM / 64;
  for (int t = 0; t < NK; ++t) {
    int sl0 = (2 * t) & 3, sl1 = sl0 ^ 1;
    int kn = (t + 1 < NK) ? (t + 1) : t;      // clamped tail restage
    int sn0 = (sl0 + 2) & 3, sn1 = sn0 ^ 1;
    int kb = kn * 64;
    short8 a[4], b[4];

    asm volatile("s_waitcnt vmcnt(4)" ::: "memory");
    __builtin_amdgcn_s_barrier();
    // phase 0: kk0, mi 0..3 (+B), stage A-kk0(t+1)
    FFN_PHASE_READS(sl0, 0, a, b, 1)
    stageA(kb, sn0);
    FFN_PHASE_MFMA(0, a, b)
    // phase 1: kk0, mi 4..7, stage B-kk0(t+1)
    FFN_PHASE_READS(sl0, 4, a, b, 0)
    stageB(kb, sn0);
    FFN_PHASE_MFMA(4, a, b)

    asm volatile("s_waitcnt vmcnt(4)" ::: "memory");
    __builtin_amdgcn_s_barrier();
    // phase 2: kk1, mi 0..3 (+B), stage A-kk1(t+1)
    FFN_PHASE_READS(sl1, 0, a, b, 1)
    stageA(kb + 32, sn1);
    FFN_PHASE_MFMA(0, a, b)
    // phase 3: kk1, mi 4..7, stage B-kk1(t+1)
    FFN_PHASE_READS(sl1, 4, a, b, 0)
    stageB(kb + 32, sn1);
    FFN_PHASE_MFMA(4, a, b)
  }
  asm volatile("s_waitcnt vmcnt(0)" ::: "memory");

  // epilogue: pair even/odd C columns (W1/W3) via shfl_xor(1), silu*mul
  int c = lane & 15, r4 = (lane >> 4) * 4;
  bool evenc = ((c & 1) == 0);
  #pragma unroll
  for (int mi = 0; mi < 8; ++mi) {
    #pragma unroll
    for (int rg = 0; rg < 4; ++rg) {
      int gr = m0 + wm * 128 + mi * 16 + r4 + rg;
      #pragma unroll
      for (int ni = 0; ni < 4; ++ni) {
        float a1v = acc[mi][ni][rg];
        float a3v = __shfl_xor(a1v, 1);
        if (evenc && gr < cnt) {
          int f = (n0 + wn * 64 + ni * 16 + c) >> 1;
          float h = (a1v / (1.f + __expf(-a1v))) * a3v;
          hg[(size_t)(off + gr) * DF + f] = f2bf(h);
        }
      }
    }
  }
}

// ---------------- FFN pass 2 ----------------
__global__ __launch_bounds__(512, 2) void k_ffn2(
    const us* __restrict__ hg, const us* __restrict__ w2b,
    const int* __restrict__ offs, const int* __restrict__ cnts,
    float* __restrict__ ys) {
  int e = blockIdx.z;
  int cnt = cnts[e];
  int m0 = blockIdx.y * 256;
  if (m0 >= cnt) return;
  int n0 = blockIdx.x * 256;
  int off = offs[e];
  __shared__ __align__(16) short As[4][8192];
  __shared__ __align__(16) short Bs[4][8192];
  int tid = threadIdx.x, lane = tid & 63, wid = tid >> 6;

  int posun = (lane & 7) ^ ((lane >> 3) & 7);
  int rl0 = wid * 32 + ((lane >> 3) << 1) + (posun >> 2);
  int rl1 = rl0 + 16;
  int gcol = (posun & 3) * 8;
  int ar0 = m0 + rl0; if (ar0 > cnt - 1) ar0 = cnt - 1;
  int ar1 = m0 + rl1; if (ar1 > cnt - 1) ar1 = cnt - 1;
  const us* w2e = w2b + ((size_t)e << 21);
  const us* a0 = hg + (size_t)(off + ar0) * DF + gcol;
  const us* a1 = hg + (size_t)(off + ar1) * DF + gcol;
  const us* b0 = w2e + (size_t)(n0 + rl0) * DF + gcol;
  const us* b1 = w2e + (size_t)(n0 + rl1) * DF + gcol;
  int dst0 = wid * 1024, dst1 = wid * 1024 + 512;

  auto stageA = [&](int ko, int slot) {
    gload16(a0 + ko, &As[slot][dst0]);
    gload16(a1 + ko, &As[slot][dst1]);
  };
  auto stageB = [&](int ko, int slot) {
    gload16(b0 + ko, &Bs[slot][dst0]);
    gload16(b1 + ko, &Bs[slot][dst1]);
  };

  int wm = wid >> 2, wn = wid & 3;
  int fr = lane & 15, glog = lane >> 4;
  int pos = (((fr & 1) << 2) | glog) ^ ((fr >> 1) & 7);
  int aoff = (wm * 64 + (fr >> 1)) * 64 + pos * 8;
  int boff = (wn * 32 + (fr >> 1)) * 64 + pos * 8;
  f32x4 acc[8][4] = {};

  stageA(0, 0); stageB(0, 0); stageA(32, 1); stageB(32, 1);

  const int NK = DF / 64;
  for (int t = 0; t < NK; ++t) {
    int sl0 = (2 * t) & 3, sl1 = sl0 ^ 1;
    int kn = (t + 1 < NK) ? (t + 1) : t;
    int sn0 = (sl0 + 2) & 3, sn1 = sn0 ^ 1;
    int kb = kn * 64;
    short8 a[4], b[4];

    asm volatile("s_waitcnt vmcnt(4)" ::: "memory");
    __builtin_amdgcn_s_barrier();
    FFN_PHASE_READS(sl0, 0, a, b, 1)
    stageA(kb, sn0);
    FFN_PHASE_MFMA(0, a, b)
    FFN_PHASE_READS(sl0, 4, a, b, 0)
    stageB(kb, sn0);
    FFN_PHASE_MFMA(4, a, b)

    asm volatile("s_waitcnt vmcnt(4)" ::: "memory");
    __builtin_amdgcn_s_barrier();
    FFN_PHASE_READS(sl1, 0, a, b, 1)
    stageA(kb + 32, sn1);
    FFN_PHASE_MFMA(0, a, b)
    FFN_PHASE_READS(sl1, 4, a, b, 0)
    stageB(kb + 32, sn1);
    FFN_PHASE_MFMA(4, a, b)
  }
  asm volatile("s_waitcnt vmcnt(0)" ::: "memory");

  int c = lane & 15, r4 = (lane >> 4) * 4;
  #pragma unroll
  for (int mi = 0; mi < 8; ++mi) {
    #pragma unroll
    for (int rg = 0; rg < 4; ++rg) {
      int gr = m0 + wm * 128 + mi * 16 + r4 + rg;
      if (gr < cnt) {
        float* yrow = ys + (size_t)(off + gr) * DM + n0;
        #pragma unroll
        for (int ni = 0; ni < 4; ++ni)
          yrow[wn * 64 + ni * 16 + c] = acc[mi][ni][rg];
      }
    }
  }
}

// ---------------- gather ----------------
__global__ void k_gather(const float* __restrict__ ys, const int* __restrict__ pos,
                         const float2* __restrict__ gts, float* __restrict__ out) {
  int idx = blockIdx.x * blockDim.x + threadIdx.x;
  int t = idx >> 8;
  int d4 = idx & 255;
  float2 g = gts[t];
  const float4* y0 = (const float4*)(ys + (size_t)pos[2 * t] * DM) + d4;
  const float4* y1 = (const float4*)(ys + (size_t)pos[2 * t + 1] * DM) + d4;
  float4 a = *y0, b = *y1, o;
  o.x = g.x * a.x + g.y * b.x;
  o.y = g.x * a.y + g.y * b.y;
  o.z = g.x * a.z + g.y * b.z;
  o.w = g.x * a.w + g.y * b.w;
  ((float4*)out)[idx] = o;
}

// ---------------- workspace layout (bytes) ----------------
// 0        : ctrl (cntb@0, cnt1@32, offs@96, imp@128, z2@160)
// 4096     : epack  int[8192]
// 36864    : gts    float2[8192]
// 102400   : btok   int[16384]
// 167936   : pos    int[16384]
// 233472   : x_bf16   (16.78 MB)
// 17010688 : W13_bf16 interleaved (67.11 MB)  <- ys fp32 aliases after ffn1
// 84119552 : W2_bf16  (33.55 MB)
// 117673984: Hg bf16  (67.11 MB)   -> total ~176 MiB

extern "C" void kernel_launch(void* const* d_in, const int* in_sizes, int n_in,
                              void* d_out, int out_size, void* d_ws, size_t ws_size,
                              hipStream_t stream) {
  const float* x  = (const float*)d_in[0];
  const float* wr = (const float*)d_in[1];
  const float* w1 = (const float*)d_in[2];
  const float* w3 = (const float*)d_in[3];
  const float* w2 = (const float*)d_in[4];
  float* out = (float*)d_out;

  uint8_t* ws = (uint8_t*)d_ws;
  int*    cntb   = (int*)(ws + 0);
  int*    cnt1   = (int*)(ws + 32);
  int*    offs   = (int*)(ws + 96);
  float*  imp    = (float*)(ws + 128);
  float*  z2     = (float*)(ws + 160);
  int*    epack  = (int*)(ws + 4096);
  float2* gts    = (float2*)(ws + 36864);
  int*    btok   = (int*)(ws + 102400);
  int*    pos    = (int*)(ws + 167936);
  us*     xbf    = (us*)(ws + 233472);
  us*     w13    = (us*)(ws + 17010688);
  us*     w2bf   = (us*)(ws + 84119552);
  us*     hg     = (us*)(ws + 117673984);
  float*  ysb    = (float*)(ws + 17010688);

  hipMemsetAsync(ws, 0, 4096, stream);

  k_cvtw<<<dim3(2048, 3), 256, 0, stream>>>(
      (const float4*)w1, (const float4*)w3, (const float4*)w2,
      (ushort4*)w13, (ushort4*)w2bf);

  k_router<<<RT_BLOCKS, 256, 0, stream>>>(x, wr, cntb, cnt1, imp, z2, epack, gts, xbf);
  k_finalize<<<1, 64, 0, stream>>>(cntb, cnt1, imp, z2, offs, out + (size_t)NT * DM);
  k_scatter<<<8, 64, 0, stream>>>(epack, gts, offs, btok, pos);

  k_ffn1<<<dim3(16, 64, 8), 512, 0, stream>>>(xbf, w13, offs, cntb, btok, hg);
  k_ffn2<<<dim3(4, 64, 8), 512, 0, stream>>>(hg, w2bf, offs, cntb, ysb);
  k_gather<<<NT * DM / 4 / 256, 256, 0, stream>>>(ysb, pos, gts, out);
}